// Round 21
// baseline (36.780 us; speedup 1.0000x reference)
//
#include <hip/hip_runtime.h>
#include <math.h>

// B=4, L=1024, C=128, D=64; rows = B*L = 4096
#define LL   1024
#define NROW 4096
#define DD   64
#define CC   128

// leaky(z) = C1*z + C2*|z|  (slope 0.01)
#define C1H 0.505f
#define C2H 0.495f

typedef short    bf16x8 __attribute__((ext_vector_type(8)));
typedef float    f32x4  __attribute__((ext_vector_type(4)));
typedef _Float16 hf2    __attribute__((ext_vector_type(2)));

static __device__ __forceinline__ unsigned short bf16rne(float f) {
  unsigned u = __float_as_uint(f);
  u += 0x7fffu + ((u >> 16) & 1u);
  return (unsigned short)(u >> 16);
}

static __device__ __forceinline__ float rflf(float v) {
  return __uint_as_float(__builtin_amdgcn_readfirstlane(__float_as_uint(v)));
}

// unpack a packed f16 pair to two fp32 (v_cvt_f32_f16 lo/hi)
static __device__ __forceinline__ void unpkf16(unsigned u, float& lo, float& hi) {
  union { unsigned u; hf2 h; } v; v.u = u;
  lo = (float)v.h.x;
  hi = (float)v.h.y;
}

// ---------------------------------------------------------------------------
// k_proj: R16 VERBATIM (validated). 8 rows/block, 256 threads, grid 512.
// grTf frag-major: chunk(b,kc,nt,l)[j] = gr_bf16[d=nt*16+(l&15)][y=kc*32+(l>>4)*8+j]
// ---------------------------------------------------------------------------
__global__ __launch_bounds__(256) void k_proj(
    const float* __restrict__ q, const float* __restrict__ Wl,
    const float* __restrict__ Wr, const float* __restrict__ a,
    uint4* __restrict__ glg, _Float16* __restrict__ gr16,
    unsigned short* __restrict__ grTf,
    float* __restrict__ AL, float* __restrict__ AR) {
  const int bl0 = blockIdx.x * 8;        // 512 blocks, no batch straddle
  const int b = bl0 >> 10;
  const int t = threadIdx.x;
  __shared__ __align__(16) float qs[8 * CC];           // 4 KB
  __shared__ __align__(16) unsigned short trT[DD][8];  // 1 KB
  __shared__ __align__(16) _Float16 trL[8][DD];        // 1 KB

  ((float4*)qs)[t] = ((const float4*)(q + (size_t)bl0 * CC))[t];
  __syncthreads();

  const int rr = t >> 6;                 // 0..3 -> rows rr*2, rr*2+1
  const int d  = t & 63;
  const int r0 = rr * 2, r1 = rr * 2 + 1;
  const float* q0 = qs + r0 * CC;
  const float* q1 = qs + r1 * CC;

  float aL0 = 0, aL1 = 0, aR0 = 0, aR1 = 0;
  float bL0 = 0, bL1 = 0, bR0 = 0, bR1 = 0;
#pragma unroll 8
  for (int c = 0; c < CC; c += 2) {
    float wl0 = Wl[c * DD + d],       wr0 = Wr[c * DD + d];
    float wl1 = Wl[(c + 1) * DD + d], wr1 = Wr[(c + 1) * DD + d];
    aL0 = fmaf(q0[c], wl0, aL0);  bL0 = fmaf(q0[c + 1], wl1, bL0);
    aL1 = fmaf(q1[c], wl0, aL1);  bL1 = fmaf(q1[c + 1], wl1, bL1);
    aR0 = fmaf(q0[c], wr0, aR0);  bR0 = fmaf(q0[c + 1], wr1, bR0);
    aR1 = fmaf(q1[c], wr0, aR1);  bR1 = fmaf(q1[c + 1], wr1, bR1);
  }
  float gL0 = aL0 + bL0, gL1 = aL1 + bL1;
  float gR0 = aR0 + bR0, gR1 = aR1 + bR1;

  trL[r0][d] = (_Float16)gL0;
  trL[r1][d] = (_Float16)gL1;
  gr16[(size_t)(bl0 + r0) * DD + d] = (_Float16)gR0;
  gr16[(size_t)(bl0 + r1) * DD + d] = (_Float16)gR1;
  trT[d][r0] = bf16rne(gR0);
  trT[d][r1] = bf16rne(gR1);

  float av = a[d];
  float vL0 = av * gL0, vL1 = av * gL1, vR0 = av * gR0, vR1 = av * gR1;
#pragma unroll
  for (int off = 1; off < 64; off <<= 1) {
    vL0 += __shfl_xor(vL0, off, 64);
    vL1 += __shfl_xor(vL1, off, 64);
    vR0 += __shfl_xor(vR0, off, 64);
    vR1 += __shfl_xor(vR1, off, 64);
  }
  if (d == 0) {
    AL[bl0 + r0] = vL0; AL[bl0 + r1] = vL1;
    AR[bl0 + r0] = vR0; AR[bl0 + r1] = vR1;
  }
  __syncthreads();
  if (t < 64) {
    // frag-major write: d=t -> nt=d>>4, lane slot l = hi*16 + (d&15), 8 y = 16B
    const int kc = (bl0 & 1023) >> 5;
    const int hi = ((bl0 & 1023) >> 3) & 3;
    ((uint4*)grTf)[((size_t)((b * 32 + kc) * 4 + (t >> 4)) << 6) +
                   hi * 16 + (t & 15)] = *(const uint4*)&trT[t][0];
  } else if (t < 128) {
    int tt = t - 64;
    int r = tt >> 3, g = tt & 7;       // row r, granule g (d = 8g..8g+7)
    glg[(((size_t)(b * 8 + g)) << 10) + (bl0 & 1023) + r] =
        *(const uint4*)&trL[r][g * 8];
  }
}

// ---------------------------------------------------------------------------
// k_fused: 8 rows/block, 256 threads (4 y per thread), grid 512 ->
// 4 blocks/CU (same 16 waves/CU as R20 but 4 independent barrier groups:
// finer granularity overlaps prologue/barrier/tail stalls across blocks).
// Per-dblk gv loads (cross-block TLP hides them; keeps VGPR low).
// fp32 pass-1 math (R20-validated), no-max softmax, frag-major PV B-loads.
// ---------------------------------------------------------------------------
__global__ __launch_bounds__(256, 4) void k_fused(
    const uint4* __restrict__ glg, const _Float16* __restrict__ gr16,
    const unsigned short* __restrict__ grTf,
    const float* __restrict__ AL, const float* __restrict__ AR,
    const float* __restrict__ a,
    float* __restrict__ scores, float* __restrict__ yout) {
  const int bl0 = blockIdx.x * 8;        // 512 blocks
  const int b = bl0 >> 10;
  const int t = threadIdx.x;             // 0..255
  const int w = t >> 6, l = t & 63;      // 4 waves

  __shared__ __align__(16) float grL32[8 * DD];         // 2 KB fp32 gr copy
  __shared__ __align__(16) unsigned short eb[8704];     // 17 KB P frags
  __shared__ __align__(16) float sPV[4][4][8][17];      // 8.7 KB
  __shared__ __align__(16) float sSx[8][4];             // [x][wave]

  // stage gr rows into fp32 LDS: 512 f16 = 256 uints -> 512 floats
  {
    unsigned u = ((const unsigned*)(gr16 + (size_t)bl0 * DD))[t];
    float lo, hi;
    unpkf16(u, lo, hi);
    grL32[t * 2]     = lo;
    grL32[t * 2 + 1] = hi;
  }

  // a -> 64 fp32 SGPRs
  float sa[64];
#pragma unroll
  for (int k = 0; k < 16; ++k) {
    float4 av = *(const float4*)&a[k * 4];
    sa[k * 4 + 0] = rflf(av.x);
    sa[k * 4 + 1] = rflf(av.y);
    sa[k * 4 + 2] = rflf(av.z);
    sa[k * 4 + 3] = rflf(av.w);
  }

  float pr[8];
#pragma unroll
  for (int x = 0; x < 8; ++x) pr[x] = C1H * rflf(AR[bl0 + x]);

  float alv[4];
#pragma unroll
  for (int yc = 0; yc < 4; ++yc) alv[yc] = AL[b * LL + yc * 256 + t];

  float pacc[8][4];
#pragma unroll
  for (int x = 0; x < 8; ++x)
#pragma unroll
    for (int yc = 0; yc < 4; ++yc) pacc[x][yc] = 0.f;

  __syncthreads();                       // barrier 1: grL32 ready

  // ---- pass 1: fp32 e accumulation, dblk-outer (16 d per dblk, 4 y) ----
  const float4* grL4 = (const float4*)grL32;
#pragma unroll
  for (int dblk = 0; dblk < 4; ++dblk) {
    // per-dblk gl loads (sunk; hidden by cross-block TLP), unpack to fp32
    float gl32[4][16];
#pragma unroll
    for (int yc = 0; yc < 4; ++yc) {
      uint4 g0 = glg[(((size_t)(b * 8 + dblk * 2 + 0)) << 10) + yc * 256 + t];
      uint4 g1 = glg[(((size_t)(b * 8 + dblk * 2 + 1)) << 10) + yc * 256 + t];
      unpkf16(g0.x, gl32[yc][0],  gl32[yc][1]);
      unpkf16(g0.y, gl32[yc][2],  gl32[yc][3]);
      unpkf16(g0.z, gl32[yc][4],  gl32[yc][5]);
      unpkf16(g0.w, gl32[yc][6],  gl32[yc][7]);
      unpkf16(g1.x, gl32[yc][8],  gl32[yc][9]);
      unpkf16(g1.y, gl32[yc][10], gl32[yc][11]);
      unpkf16(g1.z, gl32[yc][12], gl32[yc][13]);
      unpkf16(g1.w, gl32[yc][14], gl32[yc][15]);
    }
#pragma unroll
    for (int x = 0; x < 8; ++x) {
      float4 g0 = grL4[x * 16 + dblk * 4 + 0];   // d 0..3 of this dblk
      float4 g1 = grL4[x * 16 + dblk * 4 + 1];   // d 4..7
      float4 g2 = grL4[x * 16 + dblk * 4 + 2];   // d 8..11
      float4 g3 = grL4[x * 16 + dblk * 4 + 3];   // d 12..15
#pragma unroll
      for (int yc = 0; yc < 4; ++yc) {
        const float* gl = gl32[yc];
        float s = pacc[x][yc];
        s = fmaf(fabsf(gl[0]  + g0.x), sa[dblk * 16 + 0],  s);
        s = fmaf(fabsf(gl[1]  + g0.y), sa[dblk * 16 + 1],  s);
        s = fmaf(fabsf(gl[2]  + g0.z), sa[dblk * 16 + 2],  s);
        s = fmaf(fabsf(gl[3]  + g0.w), sa[dblk * 16 + 3],  s);
        s = fmaf(fabsf(gl[4]  + g1.x), sa[dblk * 16 + 4],  s);
        s = fmaf(fabsf(gl[5]  + g1.y), sa[dblk * 16 + 5],  s);
        s = fmaf(fabsf(gl[6]  + g1.z), sa[dblk * 16 + 6],  s);
        s = fmaf(fabsf(gl[7]  + g1.w), sa[dblk * 16 + 7],  s);
        s = fmaf(fabsf(gl[8]  + g2.x), sa[dblk * 16 + 8],  s);
        s = fmaf(fabsf(gl[9]  + g2.y), sa[dblk * 16 + 9],  s);
        s = fmaf(fabsf(gl[10] + g2.z), sa[dblk * 16 + 10], s);
        s = fmaf(fabsf(gl[11] + g2.w), sa[dblk * 16 + 11], s);
        s = fmaf(fabsf(gl[12] + g3.x), sa[dblk * 16 + 12], s);
        s = fmaf(fabsf(gl[13] + g3.y), sa[dblk * 16 + 13], s);
        s = fmaf(fabsf(gl[14] + g3.z), sa[dblk * 16 + 14], s);
        s = fmaf(fabsf(gl[15] + g3.w), sa[dblk * 16 + 15], s);
        pacc[x][yc] = s;
      }
    }
  }

  // ---- e -> exp(e) directly (no-max softmax; e bounded ~|8| here) ----
  float ev[8][4], lsum[8];
#pragma unroll
  for (int x = 0; x < 8; ++x) {
    lsum[x] = 0.f;
#pragma unroll
    for (int yc = 0; yc < 4; ++yc) {
      ev[x][yc] = __expf(fmaf(C2H, pacc[x][yc], pr[x] + C1H * alv[yc]));
      lsum[x] += ev[x][yc];
    }
  }
#pragma unroll
  for (int off = 1; off < 64; off <<= 1) {
#pragma unroll
    for (int x = 0; x < 8; ++x) lsum[x] += __shfl_xor(lsum[x], off, 64);
  }
  if (l == 0) {
#pragma unroll
    for (int x = 0; x < 8; ++x) sSx[x][w] = lsum[x];
  }
  __syncthreads();                       // barrier 2

  float isv[8];
#pragma unroll
  for (int x = 0; x < 8; ++x) {
    float4 s0 = *(const float4*)&sSx[x][0];
    isv[x] = 1.0f / ((s0.x + s0.y) + (s0.z + s0.w));
  }

  // ---- P writes: fp32 scores (nontemporal) + packed bf16 frag tile ----
#pragma unroll
  for (int yc = 0; yc < 4; ++yc) {
    int y = yc * 256 + t;
    int kc = y >> 5, k32 = t & 31;
#pragma unroll
    for (int x = 0; x < 8; ++x) {
      float p = ev[x][yc] * isv[x];
      __builtin_nontemporal_store(p, &scores[((size_t)(bl0 + x) << 10) + y]);
      eb[kc * 256 + x * 32 + k32] = bf16rne(p);
    }
  }
  __syncthreads();                       // barrier 3

  // ---- pass 2: PV via MFMA, 32 kc over 4 waves (8 each); coalesced B ----
  f32x4 acc[4] = {{0.f, 0.f, 0.f, 0.f}, {0.f, 0.f, 0.f, 0.f},
                  {0.f, 0.f, 0.f, 0.f}, {0.f, 0.f, 0.f, 0.f}};
  const int row16 = l & 15, hh = l >> 4;
#pragma unroll
  for (int kk = 0; kk < 8; ++kk) {
    int kc = w * 8 + kk;
    bf16x8 af = *(const bf16x8*)&eb[kc * 256 + row16 * 32 + hh * 8];
#pragma unroll
    for (int nt = 0; nt < 4; ++nt) {
      bf16x8 bfv = *(const bf16x8*)(grTf +
          ((((size_t)((b * 32 + kc) * 4 + nt)) << 6) + l) * 8);
      acc[nt] = __builtin_amdgcn_mfma_f32_16x16x32_bf16(af, bfv, acc[nt], 0, 0, 0);
    }
  }
  if (l < 32) {
#pragma unroll
    for (int nt = 0; nt < 4; ++nt)
#pragma unroll
      for (int i = 0; i < 4; ++i)
        sPV[w][nt][hh * 4 + i][row16] = acc[nt][i];
  }
  __syncthreads();                       // barrier 4
#pragma unroll
  for (int rep = 0; rep < 2; ++rep) {
    int o = t + rep * 256;               // 0..511
    int x = o >> 6, dcol = o & 63, nt = dcol >> 4, col = dcol & 15;
    float r = 0.f;
#pragma unroll
    for (int ww = 0; ww < 4; ++ww) r += sPV[ww][nt][x][col];
    yout[(size_t)(bl0 + x) * DD + dcol] = r;
  }
}

// ---------------------------------------------------------------------------
extern "C" void kernel_launch(void* const* d_in, const int* in_sizes, int n_in,
                              void* d_out, int out_size, void* d_ws, size_t ws_size,
                              hipStream_t stream) {
  const float* q  = (const float*)d_in[0];
  // d_in[1] = keys, d_in[2] = values: unused by the reference math
  const float* Wl = (const float*)d_in[3];
  const float* Wr = (const float*)d_in[4];
  const float* a  = (const float*)d_in[5];

  float* yout = (float*)d_out;                 // (4096, 64)
  float* esc  = yout + NROW * DD;              // (4096, 1024) scores

  float* ws = (float*)d_ws;
  float* AL = ws;                               // 4096 f32
  float* AR = AL + NROW;                        // 4096 f32
  uint4* glg = (uint4*)(AR + NROW);             // 4096*8 uint4 (512 KB)
  _Float16* gr16 = (_Float16*)(glg + (size_t)NROW * 8);        // 512 KB
  unsigned short* grTf = (unsigned short*)(gr16 + (size_t)NROW * DD); // 512 KB

  k_proj <<<NROW / 8, 256, 0, stream>>>(q, Wl, Wr, a, glg, gr16, grTf, AL, AR);
  k_fused<<<NROW / 8, 256, 0, stream>>>(glg, gr16, grTf, AL, AR, a, esc, yout);
}

// Round 22
// 35.918 us; speedup vs baseline: 1.0240x; 1.0240x over previous
//
#include <hip/hip_runtime.h>
#include <math.h>

// B=4, L=1024, C=128, D=64; rows = B*L = 4096
#define LL   1024
#define NROW 4096
#define DD   64
#define CC   128

// leaky(z) = C1*z + C2*|z|  (slope 0.01)
#define C1H 0.505f
#define C2H 0.495f

typedef short    bf16x8 __attribute__((ext_vector_type(8)));
typedef float    f32x4  __attribute__((ext_vector_type(4)));
typedef _Float16 hf2    __attribute__((ext_vector_type(2)));

static __device__ __forceinline__ unsigned short bf16rne(float f) {
  unsigned u = __float_as_uint(f);
  u += 0x7fffu + ((u >> 16) & 1u);
  return (unsigned short)(u >> 16);
}

static __device__ __forceinline__ float rflf(float v) {
  return __uint_as_float(__builtin_amdgcn_readfirstlane(__float_as_uint(v)));
}

// unpack a packed f16 pair to two fp32 (v_cvt_f32_f16 lo/hi)
static __device__ __forceinline__ void unpkf16(unsigned u, float& lo, float& hi) {
  union { unsigned u; hf2 h; } v; v.u = u;
  lo = (float)v.h.x;
  hi = (float)v.h.y;
}

// ---------------------------------------------------------------------------
// k_proj: R16/R20 VERBATIM (validated). 8 rows/block, 256 threads, grid 512.
// ---------------------------------------------------------------------------
__global__ __launch_bounds__(256) void k_proj(
    const float* __restrict__ q, const float* __restrict__ Wl,
    const float* __restrict__ Wr, const float* __restrict__ a,
    uint4* __restrict__ glg, _Float16* __restrict__ gr16,
    unsigned short* __restrict__ grTf,
    float* __restrict__ AL, float* __restrict__ AR) {
  const int bl0 = blockIdx.x * 8;        // 512 blocks, no batch straddle
  const int b = bl0 >> 10;
  const int t = threadIdx.x;
  __shared__ __align__(16) float qs[8 * CC];           // 4 KB
  __shared__ __align__(16) unsigned short trT[DD][8];  // 1 KB
  __shared__ __align__(16) _Float16 trL[8][DD];        // 1 KB

  ((float4*)qs)[t] = ((const float4*)(q + (size_t)bl0 * CC))[t];
  __syncthreads();

  const int rr = t >> 6;                 // 0..3 -> rows rr*2, rr*2+1
  const int d  = t & 63;
  const int r0 = rr * 2, r1 = rr * 2 + 1;
  const float* q0 = qs + r0 * CC;
  const float* q1 = qs + r1 * CC;

  float aL0 = 0, aL1 = 0, aR0 = 0, aR1 = 0;
  float bL0 = 0, bL1 = 0, bR0 = 0, bR1 = 0;
#pragma unroll 8
  for (int c = 0; c < CC; c += 2) {
    float wl0 = Wl[c * DD + d],       wr0 = Wr[c * DD + d];
    float wl1 = Wl[(c + 1) * DD + d], wr1 = Wr[(c + 1) * DD + d];
    aL0 = fmaf(q0[c], wl0, aL0);  bL0 = fmaf(q0[c + 1], wl1, bL0);
    aL1 = fmaf(q1[c], wl0, aL1);  bL1 = fmaf(q1[c + 1], wl1, bL1);
    aR0 = fmaf(q0[c], wr0, aR0);  bR0 = fmaf(q0[c + 1], wr1, bR0);
    aR1 = fmaf(q1[c], wr0, aR1);  bR1 = fmaf(q1[c + 1], wr1, bR1);
  }
  float gL0 = aL0 + bL0, gL1 = aL1 + bL1;
  float gR0 = aR0 + bR0, gR1 = aR1 + bR1;

  trL[r0][d] = (_Float16)gL0;
  trL[r1][d] = (_Float16)gL1;
  gr16[(size_t)(bl0 + r0) * DD + d] = (_Float16)gR0;
  gr16[(size_t)(bl0 + r1) * DD + d] = (_Float16)gR1;
  trT[d][r0] = bf16rne(gR0);
  trT[d][r1] = bf16rne(gR1);

  float av = a[d];
  float vL0 = av * gL0, vL1 = av * gL1, vR0 = av * gR0, vR1 = av * gR1;
#pragma unroll
  for (int off = 1; off < 64; off <<= 1) {
    vL0 += __shfl_xor(vL0, off, 64);
    vL1 += __shfl_xor(vL1, off, 64);
    vR0 += __shfl_xor(vR0, off, 64);
    vR1 += __shfl_xor(vR1, off, 64);
  }
  if (d == 0) {
    AL[bl0 + r0] = vL0; AL[bl0 + r1] = vL1;
    AR[bl0 + r0] = vR0; AR[bl0 + r1] = vR1;
  }
  __syncthreads();
  if (t < 64) {
    // frag-major write: d=t -> nt=d>>4, lane slot l = hi*16 + (d&15), 8 y = 16B
    const int kc = (bl0 & 1023) >> 5;
    const int hi = ((bl0 & 1023) >> 3) & 3;
    ((uint4*)grTf)[((size_t)((b * 32 + kc) * 4 + (t >> 4)) << 6) +
                   hi * 16 + (t & 15)] = *(const uint4*)&trT[t][0];
  } else if (t < 128) {
    int tt = t - 64;
    int r = tt >> 3, g = tt & 7;       // row r, granule g (d = 8g..8g+7)
    glg[(((size_t)(b * 8 + g)) << 10) + (bl0 & 1023) + r] =
        *(const uint4*)&trL[r][g * 8];
  }
}

// ---------------------------------------------------------------------------
// k_e: R20's k_fused MINUS pass-2. 8 rows, 512 thr, grid 512.
// Barriers 5 -> 2; LDS 36 KB -> ~2.3 KB. P bf16 goes straight to global ebg
// in EXACTLY the eb layout (ebg[blk*8192 + kc*256 + x*32 + k32]) -- same
// index math as R20's LDS writes, coalesced 64B runs per (wave, x).
// ---------------------------------------------------------------------------
__global__ __launch_bounds__(512, 4) void k_e(
    const uint4* __restrict__ glg, const _Float16* __restrict__ gr16,
    const float* __restrict__ AL, const float* __restrict__ AR,
    const float* __restrict__ a,
    float* __restrict__ scores, unsigned short* __restrict__ ebg) {
  const int bl0 = blockIdx.x * 8;        // 512 blocks
  const int b = bl0 >> 10;
  const int t = threadIdx.x;             // 0..511
  const int w = t >> 6, l = t & 63;

  __shared__ __align__(16) float grL32[8 * DD];         // 2 KB fp32 gr copy
  __shared__ __align__(16) float sSx[8][8];             // [x][wave]

  // ---- prefetch ALL glg tiles for this block into registers (16 x uint4) ----
  uint4 gv[4][2][2];
#pragma unroll
  for (int dblk = 0; dblk < 4; ++dblk)
#pragma unroll
    for (int yc = 0; yc < 2; ++yc)
#pragma unroll
      for (int g2 = 0; g2 < 2; ++g2)
        gv[dblk][yc][g2] =
            glg[(((size_t)(b * 8 + dblk * 2 + g2)) << 10) + yc * 512 + t];

  // stage gr rows into fp32 LDS: 512 f16 = 256 uints -> 512 floats
  if (t < 256) {
    unsigned u = ((const unsigned*)(gr16 + (size_t)bl0 * DD))[t];
    float lo, hi;
    unpkf16(u, lo, hi);
    grL32[t * 2]     = lo;
    grL32[t * 2 + 1] = hi;
  }

  // a -> 64 fp32 SGPRs
  float sa[64];
#pragma unroll
  for (int k = 0; k < 16; ++k) {
    float4 av = *(const float4*)&a[k * 4];
    sa[k * 4 + 0] = rflf(av.x);
    sa[k * 4 + 1] = rflf(av.y);
    sa[k * 4 + 2] = rflf(av.z);
    sa[k * 4 + 3] = rflf(av.w);
  }

  float pr[8];
#pragma unroll
  for (int x = 0; x < 8; ++x) pr[x] = C1H * rflf(AR[bl0 + x]);

  float alv[2];
  alv[0] = AL[b * LL + t];
  alv[1] = AL[b * LL + 512 + t];

  float pacc[8][2];
#pragma unroll
  for (int x = 0; x < 8; ++x) { pacc[x][0] = 0.f; pacc[x][1] = 0.f; }

  __syncthreads();                       // barrier 1: grL32 ready

  // ---- pass 1: fp32 e accumulation, dblk-outer (R20 verbatim) ----
  const float4* grL4 = (const float4*)grL32;
#pragma unroll
  for (int dblk = 0; dblk < 4; ++dblk) {
    float gl32[2][16];
#pragma unroll
    for (int yc = 0; yc < 2; ++yc) {
      unpkf16(gv[dblk][yc][0].x, gl32[yc][0],  gl32[yc][1]);
      unpkf16(gv[dblk][yc][0].y, gl32[yc][2],  gl32[yc][3]);
      unpkf16(gv[dblk][yc][0].z, gl32[yc][4],  gl32[yc][5]);
      unpkf16(gv[dblk][yc][0].w, gl32[yc][6],  gl32[yc][7]);
      unpkf16(gv[dblk][yc][1].x, gl32[yc][8],  gl32[yc][9]);
      unpkf16(gv[dblk][yc][1].y, gl32[yc][10], gl32[yc][11]);
      unpkf16(gv[dblk][yc][1].z, gl32[yc][12], gl32[yc][13]);
      unpkf16(gv[dblk][yc][1].w, gl32[yc][14], gl32[yc][15]);
    }
#pragma unroll
    for (int x = 0; x < 8; ++x) {
      float4 g0 = grL4[x * 16 + dblk * 4 + 0];
      float4 g1 = grL4[x * 16 + dblk * 4 + 1];
      float4 g2 = grL4[x * 16 + dblk * 4 + 2];
      float4 g3 = grL4[x * 16 + dblk * 4 + 3];
#pragma unroll
      for (int yc = 0; yc < 2; ++yc) {
        const float* gl = gl32[yc];
        float s = pacc[x][yc];
        s = fmaf(fabsf(gl[0]  + g0.x), sa[dblk * 16 + 0],  s);
        s = fmaf(fabsf(gl[1]  + g0.y), sa[dblk * 16 + 1],  s);
        s = fmaf(fabsf(gl[2]  + g0.z), sa[dblk * 16 + 2],  s);
        s = fmaf(fabsf(gl[3]  + g0.w), sa[dblk * 16 + 3],  s);
        s = fmaf(fabsf(gl[4]  + g1.x), sa[dblk * 16 + 4],  s);
        s = fmaf(fabsf(gl[5]  + g1.y), sa[dblk * 16 + 5],  s);
        s = fmaf(fabsf(gl[6]  + g1.z), sa[dblk * 16 + 6],  s);
        s = fmaf(fabsf(gl[7]  + g1.w), sa[dblk * 16 + 7],  s);
        s = fmaf(fabsf(gl[8]  + g2.x), sa[dblk * 16 + 8],  s);
        s = fmaf(fabsf(gl[9]  + g2.y), sa[dblk * 16 + 9],  s);
        s = fmaf(fabsf(gl[10] + g2.z), sa[dblk * 16 + 10], s);
        s = fmaf(fabsf(gl[11] + g2.w), sa[dblk * 16 + 11], s);
        s = fmaf(fabsf(gl[12] + g3.x), sa[dblk * 16 + 12], s);
        s = fmaf(fabsf(gl[13] + g3.y), sa[dblk * 16 + 13], s);
        s = fmaf(fabsf(gl[14] + g3.z), sa[dblk * 16 + 14], s);
        s = fmaf(fabsf(gl[15] + g3.w), sa[dblk * 16 + 15], s);
        pacc[x][yc] = s;
      }
    }
  }

  // ---- e -> exp(e) directly (no-max softmax) ----
  float ev[8][2], lsum[8];
#pragma unroll
  for (int x = 0; x < 8; ++x) {
    ev[x][0] = __expf(fmaf(C2H, pacc[x][0], pr[x] + C1H * alv[0]));
    ev[x][1] = __expf(fmaf(C2H, pacc[x][1], pr[x] + C1H * alv[1]));
    lsum[x] = ev[x][0] + ev[x][1];
  }
#pragma unroll
  for (int off = 1; off < 64; off <<= 1) {
#pragma unroll
    for (int x = 0; x < 8; ++x) lsum[x] += __shfl_xor(lsum[x], off, 64);
  }
  if (l == 0) {
#pragma unroll
    for (int x = 0; x < 8; ++x) sSx[x][w] = lsum[x];
  }
  __syncthreads();                       // barrier 2

  float isv[8];
#pragma unroll
  for (int x = 0; x < 8; ++x) {
    float4 s0 = *(const float4*)&sSx[x][0];
    float4 s1 = *(const float4*)&sSx[x][4];
    isv[x] = 1.0f / (((s0.x + s0.y) + (s0.z + s0.w)) +
                     ((s1.x + s1.y) + (s1.z + s1.w)));
  }

  // ---- P: fp32 scores + bf16 ebg (global, eb-identical layout) ----
  const size_t eb0 = (size_t)blockIdx.x * 8192;
#pragma unroll
  for (int yc = 0; yc < 2; ++yc) {
    int y = yc * 512 + t;
    int kc = y >> 5, k32 = t & 31;
#pragma unroll
    for (int x = 0; x < 8; ++x) {
      float p = ev[x][yc] * isv[x];
      __builtin_nontemporal_store(p, &scores[((size_t)(bl0 + x) << 10) + y]);
      __builtin_nontemporal_store(bf16rne(p), &ebg[eb0 + kc * 256 + x * 32 + k32]);
    }
  }
}

// ---------------------------------------------------------------------------
// k_pv: R20's pass-2 VERBATIM, as its own kernel. 8 rows/block, 512 thr,
// grid 512. A-frags from ebg (global; same offsets as R20's LDS eb reads --
// garbage rows 8..15 read neighbor/pad data, never used in D rows 0..7).
// ---------------------------------------------------------------------------
__global__ __launch_bounds__(512, 4) void k_pv(
    const unsigned short* __restrict__ ebg,
    const unsigned short* __restrict__ grTf,
    float* __restrict__ yout) {
  const int bl0 = blockIdx.x * 8;        // 512 blocks
  const int b = bl0 >> 10;
  const int t = threadIdx.x;             // 0..511
  const int w = t >> 6, l = t & 63;

  __shared__ __align__(16) float sPV[8][4][8][17];      // 17 KB

  f32x4 acc[4] = {{0.f, 0.f, 0.f, 0.f}, {0.f, 0.f, 0.f, 0.f},
                  {0.f, 0.f, 0.f, 0.f}, {0.f, 0.f, 0.f, 0.f}};
  const int row16 = l & 15, hh = l >> 4;
  const size_t eb0 = (size_t)blockIdx.x * 8192;
#pragma unroll
  for (int kk = 0; kk < 4; ++kk) {
    int kc = w * 4 + kk;
    bf16x8 af = *(const bf16x8*)&ebg[eb0 + kc * 256 + row16 * 32 + hh * 8];
#pragma unroll
    for (int nt = 0; nt < 4; ++nt) {
      bf16x8 bfv = *(const bf16x8*)(grTf +
          ((((size_t)((b * 32 + kc) * 4 + nt)) << 6) + l) * 8);
      acc[nt] = __builtin_amdgcn_mfma_f32_16x16x32_bf16(af, bfv, acc[nt], 0, 0, 0);
    }
  }
  if (l < 32) {
#pragma unroll
    for (int nt = 0; nt < 4; ++nt)
#pragma unroll
      for (int i = 0; i < 4; ++i)
        sPV[w][nt][hh * 4 + i][row16] = acc[nt][i];
  }
  __syncthreads();
  {
    int x = t >> 6, dcol = t & 63, nt = dcol >> 4, col = dcol & 15;
    float r = 0.f;
#pragma unroll
    for (int ww = 0; ww < 8; ++ww) r += sPV[ww][nt][x][col];
    yout[(size_t)(bl0 + x) * DD + dcol] = r;
  }
}

// ---------------------------------------------------------------------------
extern "C" void kernel_launch(void* const* d_in, const int* in_sizes, int n_in,
                              void* d_out, int out_size, void* d_ws, size_t ws_size,
                              hipStream_t stream) {
  const float* q  = (const float*)d_in[0];
  // d_in[1] = keys, d_in[2] = values: unused by the reference math
  const float* Wl = (const float*)d_in[3];
  const float* Wr = (const float*)d_in[4];
  const float* a  = (const float*)d_in[5];

  float* yout = (float*)d_out;                 // (4096, 64)
  float* esc  = yout + NROW * DD;              // (4096, 1024) scores

  float* ws = (float*)d_ws;
  float* AL = ws;                               // 4096 f32
  float* AR = AL + NROW;                        // 4096 f32
  uint4* glg = (uint4*)(AR + NROW);             // 4096*8 uint4 (512 KB)
  _Float16* gr16 = (_Float16*)(glg + (size_t)NROW * 8);        // 512 KB
  unsigned short* grTf = (unsigned short*)(gr16 + (size_t)NROW * DD); // 512 KB
  unsigned short* ebg = grTf + (size_t)NROW * LL / 4;
  // ebg: 512 blocks * 8192 bf16 + 256-elem pad for benign garbage-row reads
  // total ws use ~ 2.5 MB + 8.4 MB, well under workspace

  k_proj<<<NROW / 8, 256, 0, stream>>>(q, Wl, Wr, a, glg, gr16, grTf, AL, AR);
  k_e   <<<NROW / 8, 512, 0, stream>>>(glg, gr16, AL, AR, a, esc, ebg);
  k_pv  <<<NROW / 8, 512, 0, stream>>>(ebg, grTf, yout);
}

// Round 23
// 32.723 us; speedup vs baseline: 1.1240x; 1.0976x over previous
//
#include <hip/hip_runtime.h>
#include <math.h>

// B=4, L=1024, C=128, D=64; rows = B*L = 4096
#define LL   1024
#define NROW 4096
#define DD   64
#define CC   128

// leaky(z) = C1*z + C2*|z|  (slope 0.01)
#define C1H 0.505f
#define C2H 0.495f

typedef short    bf16x8 __attribute__((ext_vector_type(8)));
typedef float    f32x4  __attribute__((ext_vector_type(4)));
typedef _Float16 hf2    __attribute__((ext_vector_type(2)));

static __device__ __forceinline__ unsigned short bf16rne(float f) {
  unsigned u = __float_as_uint(f);
  u += 0x7fffu + ((u >> 16) & 1u);
  return (unsigned short)(u >> 16);
}

static __device__ __forceinline__ float rflf(float v) {
  return __uint_as_float(__builtin_amdgcn_readfirstlane(__float_as_uint(v)));
}

// unpack a packed f16 pair to two fp32 (v_cvt_f32_f16 lo/hi)
static __device__ __forceinline__ void unpkf16(unsigned u, float& lo, float& hi) {
  union { unsigned u; hf2 h; } v; v.u = u;
  lo = (float)v.h.x;
  hi = (float)v.h.y;
}

// ---------------------------------------------------------------------------
// k_proj: R16 VERBATIM (validated). 8 rows/block, 256 threads, grid 512.
// grTf frag-major: chunk(b,kc,nt,l)[j] = gr_bf16[d=nt*16+(l&15)][y=kc*32+(l>>4)*8+j]
// ---------------------------------------------------------------------------
__global__ __launch_bounds__(256) void k_proj(
    const float* __restrict__ q, const float* __restrict__ Wl,
    const float* __restrict__ Wr, const float* __restrict__ a,
    uint4* __restrict__ glg, _Float16* __restrict__ gr16,
    unsigned short* __restrict__ grTf,
    float* __restrict__ AL, float* __restrict__ AR) {
  const int bl0 = blockIdx.x * 8;        // 512 blocks, no batch straddle
  const int b = bl0 >> 10;
  const int t = threadIdx.x;
  __shared__ __align__(16) float qs[8 * CC];           // 4 KB
  __shared__ __align__(16) unsigned short trT[DD][8];  // 1 KB
  __shared__ __align__(16) _Float16 trL[8][DD];        // 1 KB

  ((float4*)qs)[t] = ((const float4*)(q + (size_t)bl0 * CC))[t];
  __syncthreads();

  const int rr = t >> 6;                 // 0..3 -> rows rr*2, rr*2+1
  const int d  = t & 63;
  const int r0 = rr * 2, r1 = rr * 2 + 1;
  const float* q0 = qs + r0 * CC;
  const float* q1 = qs + r1 * CC;

  float aL0 = 0, aL1 = 0, aR0 = 0, aR1 = 0;
  float bL0 = 0, bL1 = 0, bR0 = 0, bR1 = 0;
#pragma unroll 8
  for (int c = 0; c < CC; c += 2) {
    float wl0 = Wl[c * DD + d],       wr0 = Wr[c * DD + d];
    float wl1 = Wl[(c + 1) * DD + d], wr1 = Wr[(c + 1) * DD + d];
    aL0 = fmaf(q0[c], wl0, aL0);  bL0 = fmaf(q0[c + 1], wl1, bL0);
    aL1 = fmaf(q1[c], wl0, aL1);  bL1 = fmaf(q1[c + 1], wl1, bL1);
    aR0 = fmaf(q0[c], wr0, aR0);  bR0 = fmaf(q0[c + 1], wr1, bR0);
    aR1 = fmaf(q1[c], wr0, aR1);  bR1 = fmaf(q1[c + 1], wr1, bR1);
  }
  float gL0 = aL0 + bL0, gL1 = aL1 + bL1;
  float gR0 = aR0 + bR0, gR1 = aR1 + bR1;

  trL[r0][d] = (_Float16)gL0;
  trL[r1][d] = (_Float16)gL1;
  gr16[(size_t)(bl0 + r0) * DD + d] = (_Float16)gR0;
  gr16[(size_t)(bl0 + r1) * DD + d] = (_Float16)gR1;
  trT[d][r0] = bf16rne(gR0);
  trT[d][r1] = bf16rne(gR1);

  float av = a[d];
  float vL0 = av * gL0, vL1 = av * gL1, vR0 = av * gR0, vR1 = av * gR1;
#pragma unroll
  for (int off = 1; off < 64; off <<= 1) {
    vL0 += __shfl_xor(vL0, off, 64);
    vL1 += __shfl_xor(vL1, off, 64);
    vR0 += __shfl_xor(vR0, off, 64);
    vR1 += __shfl_xor(vR1, off, 64);
  }
  if (d == 0) {
    AL[bl0 + r0] = vL0; AL[bl0 + r1] = vL1;
    AR[bl0 + r0] = vR0; AR[bl0 + r1] = vR1;
  }
  __syncthreads();
  if (t < 64) {
    // frag-major write: d=t -> nt=d>>4, lane slot l = hi*16 + (d&15), 8 y = 16B
    const int kc = (bl0 & 1023) >> 5;
    const int hi = ((bl0 & 1023) >> 3) & 3;
    ((uint4*)grTf)[((size_t)((b * 32 + kc) * 4 + (t >> 4)) << 6) +
                   hi * 16 + (t & 15)] = *(const uint4*)&trT[t][0];
  } else if (t < 128) {
    int tt = t - 64;
    int r = tt >> 3, g = tt & 7;       // row r, granule g (d = 8g..8g+7)
    glg[(((size_t)(b * 8 + g)) << 10) + (bl0 & 1023) + r] =
        *(const uint4*)&trL[r][g * 8];
  }
}

// ---------------------------------------------------------------------------
// k_fused: R20 VERBATIM (best measured config, 32.8 us total).
// 8 rows, 512 thr, prefetch-all glg, fp32 pass-1 (full-rate VALU; packed-f16
// pk_add/dot2 measured slower), no-max softmax, frag-major coalesced PV B.
// ---------------------------------------------------------------------------
__global__ __launch_bounds__(512, 4) void k_fused(
    const uint4* __restrict__ glg, const _Float16* __restrict__ gr16,
    const unsigned short* __restrict__ grTf,
    const float* __restrict__ AL, const float* __restrict__ AR,
    const float* __restrict__ a,
    float* __restrict__ scores, float* __restrict__ yout) {
  const int bl0 = blockIdx.x * 8;        // 512 blocks
  const int b = bl0 >> 10;
  const int t = threadIdx.x;             // 0..511
  const int w = t >> 6, l = t & 63;

  __shared__ __align__(16) float grL32[8 * DD];         // 2 KB fp32 gr copy
  __shared__ __align__(16) unsigned short eb[8704];     // 17 KB P frags
  __shared__ __align__(16) float sPV[8][4][8][17];      // 17 KB
  __shared__ __align__(16) float sSx[8][8];             // [x][wave]

  // ---- prefetch ALL glg tiles for this block into registers (16 x uint4) ----
  uint4 gv[4][2][2];
#pragma unroll
  for (int dblk = 0; dblk < 4; ++dblk)
#pragma unroll
    for (int yc = 0; yc < 2; ++yc)
#pragma unroll
      for (int g2 = 0; g2 < 2; ++g2)
        gv[dblk][yc][g2] =
            glg[(((size_t)(b * 8 + dblk * 2 + g2)) << 10) + yc * 512 + t];

  // stage gr rows into fp32 LDS: 512 f16 = 256 uints -> 512 floats
  if (t < 256) {
    unsigned u = ((const unsigned*)(gr16 + (size_t)bl0 * DD))[t];
    float lo, hi;
    unpkf16(u, lo, hi);
    grL32[t * 2]     = lo;
    grL32[t * 2 + 1] = hi;
  }

  // a -> 64 fp32 SGPRs
  float sa[64];
#pragma unroll
  for (int k = 0; k < 16; ++k) {
    float4 av = *(const float4*)&a[k * 4];
    sa[k * 4 + 0] = rflf(av.x);
    sa[k * 4 + 1] = rflf(av.y);
    sa[k * 4 + 2] = rflf(av.z);
    sa[k * 4 + 3] = rflf(av.w);
  }

  float pr[8];
#pragma unroll
  for (int x = 0; x < 8; ++x) pr[x] = C1H * rflf(AR[bl0 + x]);

  float alv[2];
  alv[0] = AL[b * LL + t];
  alv[1] = AL[b * LL + 512 + t];

  float pacc[8][2];
#pragma unroll
  for (int x = 0; x < 8; ++x) { pacc[x][0] = 0.f; pacc[x][1] = 0.f; }

  __syncthreads();                       // barrier 1: grL32 ready

  // ---- pass 1: fp32 e accumulation, dblk-outer (16 d per dblk) ----
  const float4* grL4 = (const float4*)grL32;
#pragma unroll
  for (int dblk = 0; dblk < 4; ++dblk) {
    // unpack this dblk's gl to fp32 once (reused across 8 x)
    float gl32[2][16];
#pragma unroll
    for (int yc = 0; yc < 2; ++yc) {
      unpkf16(gv[dblk][yc][0].x, gl32[yc][0],  gl32[yc][1]);
      unpkf16(gv[dblk][yc][0].y, gl32[yc][2],  gl32[yc][3]);
      unpkf16(gv[dblk][yc][0].z, gl32[yc][4],  gl32[yc][5]);
      unpkf16(gv[dblk][yc][0].w, gl32[yc][6],  gl32[yc][7]);
      unpkf16(gv[dblk][yc][1].x, gl32[yc][8],  gl32[yc][9]);
      unpkf16(gv[dblk][yc][1].y, gl32[yc][10], gl32[yc][11]);
      unpkf16(gv[dblk][yc][1].z, gl32[yc][12], gl32[yc][13]);
      unpkf16(gv[dblk][yc][1].w, gl32[yc][14], gl32[yc][15]);
    }
#pragma unroll
    for (int x = 0; x < 8; ++x) {
      float4 g0 = grL4[x * 16 + dblk * 4 + 0];   // d 0..3 of this dblk
      float4 g1 = grL4[x * 16 + dblk * 4 + 1];   // d 4..7
      float4 g2 = grL4[x * 16 + dblk * 4 + 2];   // d 8..11
      float4 g3 = grL4[x * 16 + dblk * 4 + 3];   // d 12..15
#pragma unroll
      for (int yc = 0; yc < 2; ++yc) {
        const float* gl = gl32[yc];
        float s = pacc[x][yc];
        s = fmaf(fabsf(gl[0]  + g0.x), sa[dblk * 16 + 0],  s);
        s = fmaf(fabsf(gl[1]  + g0.y), sa[dblk * 16 + 1],  s);
        s = fmaf(fabsf(gl[2]  + g0.z), sa[dblk * 16 + 2],  s);
        s = fmaf(fabsf(gl[3]  + g0.w), sa[dblk * 16 + 3],  s);
        s = fmaf(fabsf(gl[4]  + g1.x), sa[dblk * 16 + 4],  s);
        s = fmaf(fabsf(gl[5]  + g1.y), sa[dblk * 16 + 5],  s);
        s = fmaf(fabsf(gl[6]  + g1.z), sa[dblk * 16 + 6],  s);
        s = fmaf(fabsf(gl[7]  + g1.w), sa[dblk * 16 + 7],  s);
        s = fmaf(fabsf(gl[8]  + g2.x), sa[dblk * 16 + 8],  s);
        s = fmaf(fabsf(gl[9]  + g2.y), sa[dblk * 16 + 9],  s);
        s = fmaf(fabsf(gl[10] + g2.z), sa[dblk * 16 + 10], s);
        s = fmaf(fabsf(gl[11] + g2.w), sa[dblk * 16 + 11], s);
        s = fmaf(fabsf(gl[12] + g3.x), sa[dblk * 16 + 12], s);
        s = fmaf(fabsf(gl[13] + g3.y), sa[dblk * 16 + 13], s);
        s = fmaf(fabsf(gl[14] + g3.z), sa[dblk * 16 + 14], s);
        s = fmaf(fabsf(gl[15] + g3.w), sa[dblk * 16 + 15], s);
        pacc[x][yc] = s;
      }
    }
  }

  // ---- e -> exp(e) directly (no-max softmax; e bounded ~|8| here) ----
  float ev[8][2], lsum[8];
#pragma unroll
  for (int x = 0; x < 8; ++x) {
    ev[x][0] = __expf(fmaf(C2H, pacc[x][0], pr[x] + C1H * alv[0]));
    ev[x][1] = __expf(fmaf(C2H, pacc[x][1], pr[x] + C1H * alv[1]));
    lsum[x] = ev[x][0] + ev[x][1];
  }
#pragma unroll
  for (int off = 1; off < 64; off <<= 1) {
#pragma unroll
    for (int x = 0; x < 8; ++x) lsum[x] += __shfl_xor(lsum[x], off, 64);
  }
  if (l == 0) {
#pragma unroll
    for (int x = 0; x < 8; ++x) sSx[x][w] = lsum[x];
  }
  __syncthreads();                       // barrier 2

  float isv[8];
#pragma unroll
  for (int x = 0; x < 8; ++x) {
    float4 s0 = *(const float4*)&sSx[x][0];
    float4 s1 = *(const float4*)&sSx[x][4];
    isv[x] = 1.0f / (((s0.x + s0.y) + (s0.z + s0.w)) +
                     ((s1.x + s1.y) + (s1.z + s1.w)));
  }

  // ---- P writes: fp32 scores (nontemporal) + packed bf16 frag tile ----
#pragma unroll
  for (int yc = 0; yc < 2; ++yc) {
    int y = yc * 512 + t;
    int kc = y >> 5, k32 = t & 31;
#pragma unroll
    for (int x = 0; x < 8; ++x) {
      float p = ev[x][yc] * isv[x];
      __builtin_nontemporal_store(p, &scores[((size_t)(bl0 + x) << 10) + y]);
      eb[kc * 256 + x * 32 + k32] = bf16rne(p);
    }
  }
  __syncthreads();                       // barrier 3

  // ---- pass 2: PV via MFMA, kc split across 8 waves; coalesced B ----
  f32x4 acc[4] = {{0.f, 0.f, 0.f, 0.f}, {0.f, 0.f, 0.f, 0.f},
                  {0.f, 0.f, 0.f, 0.f}, {0.f, 0.f, 0.f, 0.f}};
  const int row16 = l & 15, hh = l >> 4;
#pragma unroll
  for (int kk = 0; kk < 4; ++kk) {
    int kc = w * 4 + kk;
    bf16x8 af = *(const bf16x8*)&eb[kc * 256 + row16 * 32 + hh * 8];
#pragma unroll
    for (int nt = 0; nt < 4; ++nt) {
      bf16x8 bfv = *(const bf16x8*)(grTf +
          ((((size_t)((b * 32 + kc) * 4 + nt)) << 6) + l) * 8);
      acc[nt] = __builtin_amdgcn_mfma_f32_16x16x32_bf16(af, bfv, acc[nt], 0, 0, 0);
    }
  }
  if (l < 32) {
#pragma unroll
    for (int nt = 0; nt < 4; ++nt)
#pragma unroll
      for (int i = 0; i < 4; ++i)
        sPV[w][nt][hh * 4 + i][row16] = acc[nt][i];
  }
  __syncthreads();                       // barrier 4
  {
    int x = t >> 6, dcol = t & 63, nt = dcol >> 4, col = dcol & 15;
    float r = 0.f;
#pragma unroll
    for (int ww = 0; ww < 8; ++ww) r += sPV[ww][nt][x][col];
    yout[(size_t)(bl0 + x) * DD + dcol] = r;
  }
}

// ---------------------------------------------------------------------------
extern "C" void kernel_launch(void* const* d_in, const int* in_sizes, int n_in,
                              void* d_out, int out_size, void* d_ws, size_t ws_size,
                              hipStream_t stream) {
  const float* q  = (const float*)d_in[0];
  // d_in[1] = keys, d_in[2] = values: unused by the reference math
  const float* Wl = (const float*)d_in[3];
  const float* Wr = (const float*)d_in[4];
  const float* a  = (const float*)d_in[5];

  float* yout = (float*)d_out;                 // (4096, 64)
  float* esc  = yout + NROW * DD;              // (4096, 1024) scores

  float* ws = (float*)d_ws;
  float* AL = ws;                               // 4096 f32
  float* AR = AL + NROW;                        // 4096 f32
  uint4* glg = (uint4*)(AR + NROW);             // 4096*8 uint4 (512 KB)
  _Float16* gr16 = (_Float16*)(glg + (size_t)NROW * 8);        // 512 KB
  unsigned short* grTf = (unsigned short*)(gr16 + (size_t)NROW * DD); // 512 KB

  k_proj <<<NROW / 8, 256, 0, stream>>>(q, Wl, Wr, a, glg, gr16, grTf, AL, AR);
  k_fused<<<NROW / 8, 512, 0, stream>>>(glg, gr16, grTf, AL, AR, a, esc, yout);
}